// Round 5
// baseline (49.116 us; speedup 1.0000x reference)
//
#include <hip/hip_runtime.h>
#include <hip/hip_bf16.h>

// Forward warp (bilinear splatting), direct per-tile gather-from-window.
//   img  [B=8, C=3, H=180, W=320] f32
//   flow [B=8, 2,  H=180, W=320] f32
//   scale=4 -> out [B, C, 720, 1280] f32
//
// Each output tile (80x64) gathers from a fixed 38x34 input window (valid when
// |flow| <= 8; exact window is [ -M, TH/4+M-1 ] x [ -M, TW/4+M-1 ] around the
// tile origin /4, +1 slack each side for fp edge cases). Pixels with
// |flow| > 8 are excluded by the EXACT same predicate and splatted with global
// atomics in a second kernel (expected ~58 such pixels for N(0,2)*2 flow, but
// correctness is exact for ANY input). Tile pass writes the whole output with
// exclusive float4 stores -> no memset, no workspace.
//
// LDS acc: 3 planes with stride padded to 5124 floats (5124 % 32 == 4) so one
// pixel's 3 channel atomics hit banks b, b+4, b+8 (distinct) and float4
// readback stays 16B-aligned and conflict-free.

#define B_ 8
#define C_ 3
#define H_ 180
#define W_ 320
#define HW_ (H_ * W_)
#define SCALE_ 4
#define Ho_ (H_ * SCALE_)            // 720
#define Wo_ (W_ * SCALE_)            // 1280
#define TH_ 80
#define TW_ 64
#define NTY_ (Ho_ / TH_)             // 9
#define NTX_ (Wo_ / TW_)             // 20
#define NTILES_ (B_ * NTY_ * NTX_)   // 1440
#define NPIX_ (B_ * H_ * W_)         // 460800 (= 1800 * 256)

#define MARGIN_ 8.0f
#define MARGIN_I_ 8
#define WIN_H_ (TH_ / 4 + 2 * MARGIN_I_ + 2)   // 38
#define WIN_W_ (TW_ / 4 + 2 * MARGIN_I_ + 2)   // 34
#define PLANE_STRIDE_ 5124                     // TH_*TW_=5120, +4 (mod 32 == 4, 16B-aligned)
#define LDS_FLOATS_ (C_ * PLANE_STRIDE_)       // 15372

__global__ __launch_bounds__(512) void warp_tile_kernel(const float* __restrict__ img,
                                                        const float* __restrict__ flow,
                                                        float* __restrict__ out) {
    __shared__ __align__(16) float acc[LDS_FLOATS_];
    const int tile = blockIdx.x;
    const int tx = tile % NTX_;
    const int tt = tile / NTX_;
    const int ty = tt % NTY_;
    const int b  = tt / NTY_;
    const int px0 = tx * TW_;
    const int py0 = ty * TH_;

    for (int j = threadIdx.x; j < LDS_FLOATS_ / 4; j += 512)
        *reinterpret_cast<float4*>(&acc[j * 4]) = make_float4(0.f, 0.f, 0.f, 0.f);
    __syncthreads();

    const float* __restrict__ fxp  = flow + (size_t)(b * 2 + 0) * HW_;
    const float* __restrict__ fyp  = flow + (size_t)(b * 2 + 1) * HW_;
    const float* __restrict__ imgb = img + (size_t)b * C_ * HW_;

    const int hb = py0 >> 2;
    const int wb = px0 >> 2;

    for (int i = threadIdx.x; i < WIN_H_ * WIN_W_; i += 512) {
        int r = i / WIN_W_;
        int c = i - r * WIN_W_;
        int h = hb - (MARGIN_I_ + 1) + r;
        int w = wb - (MARGIN_I_ + 1) + c;
        if ((unsigned)h >= (unsigned)H_ || (unsigned)w >= (unsigned)W_) continue;
        int hw = h * W_ + w;
        float fx = fxp[hw];
        float fy = fyp[hw];
        // Must be the EXACT complement of outlier_kernel's predicate.
        if (!(fabsf(fx) <= MARGIN_ && fabsf(fy) <= MARGIN_)) continue;

        float x = ((float)w + fx) * (float)SCALE_;
        float y = ((float)h + fy) * (float)SCALE_;
        float x0f = floorf(x), y0f = floorf(y);
        int ix0 = (int)x0f - px0;   // tile-local
        int iy0 = (int)y0f - py0;
        bool cx0 = (unsigned)ix0 < (unsigned)TW_;
        bool cx1 = (unsigned)(ix0 + 1) < (unsigned)TW_;
        bool cy0 = (unsigned)iy0 < (unsigned)TH_;
        bool cy1 = (unsigned)(iy0 + 1) < (unsigned)TH_;
        if (!((cx0 | cx1) & (cy0 | cy1))) continue;

        float ax = x - x0f, ay = y - y0f;
        float v0 = imgb[hw];
        float v1 = imgb[HW_ + hw];
        float v2 = imgb[2 * HW_ + hw];
        float wxs[2] = {1.0f - ax, ax};
        float wys[2] = {1.0f - ay, ay};
        bool cxs[2] = {cx0, cx1};
        bool cys[2] = {cy0, cy1};
        #pragma unroll
        for (int ky = 0; ky < 2; ++ky) {
            if (!cys[ky]) continue;
            #pragma unroll
            for (int kx = 0; kx < 2; ++kx) {
                if (!cxs[kx]) continue;
                float wt = wxs[kx] * wys[ky];
                int la = (iy0 + ky) * TW_ + (ix0 + kx);
                atomicAdd(&acc[la], v0 * wt);
                atomicAdd(&acc[la + PLANE_STRIDE_], v1 * wt);
                atomicAdd(&acc[la + 2 * PLANE_STRIDE_], v2 * wt);
            }
        }
    }
    __syncthreads();

    // exclusive coalesced float4 write-out (overwrites poison -> no memset)
    const size_t outb = (size_t)b * C_ * Ho_ * Wo_;
    const int F4_PER_PLANE = TH_ * TW_ / 4;        // 1280
    const int F4_PER_ROW   = TW_ / 4;              // 16
    for (int j = threadIdx.x; j < C_ * F4_PER_PLANE; j += 512) {
        int ch  = j / F4_PER_PLANE;
        int rem = j - ch * F4_PER_PLANE;
        int yy  = rem / F4_PER_ROW;
        int xx4 = rem - yy * F4_PER_ROW;
        *reinterpret_cast<float4*>(
            &out[outb + (size_t)ch * Ho_ * Wo_ + (size_t)(py0 + yy) * Wo_ + px0 + xx4 * 4]) =
            *reinterpret_cast<const float4*>(&acc[ch * PLANE_STRIDE_ + yy * TW_ + xx4 * 4]);
    }
}

// Pixels with |flow| > MARGIN_: exact global-atomic splat (runs AFTER tile writes).
__global__ __launch_bounds__(256) void outlier_kernel(const float* __restrict__ img,
                                                      const float* __restrict__ flow,
                                                      float* __restrict__ out) {
    int idx = blockIdx.x * 256 + threadIdx.x;   // grid exactly NPIX_/256
    int w = idx % W_;
    int t = idx / W_;
    int h = t % H_;
    int b = t / H_;
    int hw = h * W_ + w;
    float fx = flow[(b * 2 + 0) * HW_ + hw];
    float fy = flow[(b * 2 + 1) * HW_ + hw];
    if (fabsf(fx) <= MARGIN_ && fabsf(fy) <= MARGIN_) return;   // handled by tile pass

    float x = ((float)w + fx) * (float)SCALE_;
    float y = ((float)h + fy) * (float)SCALE_;
    float x0f = floorf(x), y0f = floorf(y);
    float ax = x - x0f, ay = y - y0f;
    int ix0 = (int)x0f, iy0 = (int)y0f;
    const float* imgb = img + (size_t)b * C_ * HW_;
    float v0 = imgb[hw];
    float v1 = imgb[HW_ + hw];
    float v2 = imgb[2 * HW_ + hw];
    const size_t out_b = (size_t)b * C_ * Ho_ * Wo_;
    const size_t chs = (size_t)Ho_ * Wo_;
    float wxs[2] = {1.0f - ax, ax};
    float wys[2] = {1.0f - ay, ay};
    #pragma unroll
    for (int ky = 0; ky < 2; ++ky) {
        int yi = iy0 + ky;
        if ((unsigned)yi >= (unsigned)Ho_) continue;
        #pragma unroll
        for (int kx = 0; kx < 2; ++kx) {
            int xi = ix0 + kx;
            if ((unsigned)xi >= (unsigned)Wo_) continue;
            float wt = wxs[kx] * wys[ky];
            size_t base = out_b + (size_t)yi * Wo_ + (size_t)xi;
            atomicAdd(&out[base + 0 * chs], v0 * wt);
            atomicAdd(&out[base + 1 * chs], v1 * wt);
            atomicAdd(&out[base + 2 * chs], v2 * wt);
        }
    }
}

// ---------------- fallback: naive global-atomic splat (scale != 4) ----------------
__global__ __launch_bounds__(256) void splat_naive(const float* __restrict__ img,
                                                   const float* __restrict__ flow,
                                                   const int* __restrict__ scale_p,
                                                   float* __restrict__ out) {
    int idx = blockIdx.x * blockDim.x + threadIdx.x;
    if (idx >= NPIX_) return;
    const int s = *scale_p;
    const int Ho = H_ * s, Wo = W_ * s;
    int w = idx % W_;
    int t = idx / W_;
    int h = t % H_;
    int b = t / H_;
    const int hw = h * W_ + w;
    float fx = flow[((b * 2 + 0) * H_) * W_ + hw];
    float fy = flow[((b * 2 + 1) * H_) * W_ + hw];
    float x = ((float)w + fx) * (float)s;
    float y = ((float)h + fy) * (float)s;
    float x0f = floorf(x), y0f = floorf(y);
    float ax = x - x0f, ay = y - y0f;
    int ix0 = (int)x0f, iy0 = (int)y0f;
    const size_t img_b = (size_t)b * C_ * HW_;
    float v0 = img[img_b + 0 * (size_t)HW_ + hw];
    float v1 = img[img_b + 1 * (size_t)HW_ + hw];
    float v2 = img[img_b + 2 * (size_t)HW_ + hw];
    const size_t out_b = (size_t)b * C_ * Ho * Wo;
    const size_t out_chs = (size_t)Ho * Wo;
    float wxs[2] = {1.0f - ax, ax};
    float wys[2] = {1.0f - ay, ay};
    #pragma unroll
    for (int ky = 0; ky < 2; ++ky) {
        int yi = iy0 + ky;
        if (yi < 0 || yi > Ho - 1) continue;
        #pragma unroll
        for (int kx = 0; kx < 2; ++kx) {
            int xi = ix0 + kx;
            if (xi < 0 || xi > Wo - 1) continue;
            float wt = wxs[kx] * wys[ky];
            size_t base = out_b + (size_t)yi * Wo + (size_t)xi;
            atomicAdd(&out[base + 0 * out_chs], v0 * wt);
            atomicAdd(&out[base + 1 * out_chs], v1 * wt);
            atomicAdd(&out[base + 2 * out_chs], v2 * wt);
        }
    }
}

extern "C" void kernel_launch(void* const* d_in, const int* in_sizes, int n_in,
                              void* d_out, int out_size, void* d_ws, size_t ws_size,
                              hipStream_t stream) {
    const float* img   = (const float*)d_in[0];
    const float* flow  = (const float*)d_in[1];
    const int*   scale = (const int*)d_in[2];
    float* out = (float*)d_out;

    const bool scale4 = (out_size == B_ * C_ * Ho_ * Wo_);

    if (scale4) {
        warp_tile_kernel<<<NTILES_, 512, 0, stream>>>(img, flow, out);
        outlier_kernel<<<NPIX_ / 256, 256, 0, stream>>>(img, flow, out);
    } else {
        hipMemsetAsync(out, 0, (size_t)out_size * sizeof(float), stream);
        splat_naive<<<(NPIX_ + 255) / 256, 256, 0, stream>>>(img, flow, scale, out);
    }
}

// Round 7
// 43.733 us; speedup vs baseline: 1.1231x; 1.1231x over previous
//
#include <hip/hip_runtime.h>
#include <hip/hip_bf16.h>

// Forward warp (bilinear splatting), direct per-tile gather-from-window.
//   img  [B=8, C=3, H=180, W=320] f32
//   flow [B=8, 2,  H=180, W=320] f32
//   scale=4 -> out [B, C, 720, 1280] f32
//
// Tile 40x64, margin 8: window 28x34=952 input px per tile. Pixels with
// |flow| > 8 are excluded by the EXACT same predicate and splatted with
// global atomics in a second kernel (expected ~60 pixels for this flow
// distribution; exact for ANY input). Tile pass writes the whole output
// with exclusive nontemporal float4 stores -> no memset, no workspace.
//
// Latency fix: each thread batches its ~4 window items and issues ALL
// flow+img loads up front (independent), then computes + LDS-atomics.
// Occupancy: 30.8 KB LDS, 256 threads -> 5 blocks/CU = 20 waves/CU.

typedef float f32x4 __attribute__((ext_vector_type(4)));

#define B_ 8
#define C_ 3
#define H_ 180
#define W_ 320
#define HW_ (H_ * W_)
#define SCALE_ 4
#define Ho_ (H_ * SCALE_)            // 720
#define Wo_ (W_ * SCALE_)            // 1280
#define TH_ 40
#define TW_ 64
#define NTY_ (Ho_ / TH_)             // 18
#define NTX_ (Wo_ / TW_)             // 20
#define NTILES_ (B_ * NTY_ * NTX_)   // 2880 (divisible by 8 -> bijective XCD swizzle)
#define NPIX_ (B_ * H_ * W_)         // 460800

#define MARGIN_ 8.0f
#define MARGIN_I_ 8
#define WIN_H_ (TH_ / 4 + 2 * MARGIN_I_ + 2)   // 28
#define WIN_W_ (TW_ / 4 + 2 * MARGIN_I_ + 2)   // 34
#define WIN_ITEMS_ (WIN_H_ * WIN_W_)           // 952  (<= 4*256)
#define PLANE_STRIDE_ 2564                     // 2560+4: channels -> distinct banks, 16B-aligned
#define LDS_FLOATS_ (C_ * PLANE_STRIDE_)       // 7692 floats = 30768 B -> 5 blocks/CU

__global__ __launch_bounds__(256) void warp_tile_kernel(const float* __restrict__ img,
                                                        const float* __restrict__ flow,
                                                        float* __restrict__ out) {
    __shared__ __align__(16) float acc[LDS_FLOATS_];

    // XCD-chunked swizzle: consecutive hardware blockIdx round-robin across the
    // 8 XCDs; remap so each XCD owns a contiguous (spatially local) tile range.
    int tile = (int)(blockIdx.x & 7) * (NTILES_ / 8) + (int)(blockIdx.x >> 3);
    const int tx = tile % NTX_;
    const int tt = tile / NTX_;
    const int ty = tt % NTY_;
    const int b  = tt / NTY_;
    const int px0 = tx * TW_;
    const int py0 = ty * TH_;

    for (int j = threadIdx.x; j < LDS_FLOATS_ / 4; j += 256)
        *reinterpret_cast<f32x4*>(&acc[j * 4]) = (f32x4)(0.f);
    __syncthreads();

    const float* __restrict__ fxp  = flow + (size_t)(b * 2 + 0) * HW_;
    const float* __restrict__ fyp  = flow + (size_t)(b * 2 + 1) * HW_;
    const float* __restrict__ imgb = img + (size_t)b * C_ * HW_;

    const int hb = py0 >> 2;
    const int wb = px0 >> 2;

    // ---- phase 1: batched independent loads (break dependent-latency chains) ----
    float fxv[4], fyv[4], v0v[4], v1v[4], v2v[4];
    int hv[4], wv[4];
    bool av[4];
    #pragma unroll
    for (int k = 0; k < 4; ++k) {
        int i = (int)threadIdx.x + k * 256;
        int r = i / WIN_W_;
        int c = i - r * WIN_W_;
        int h = hb - (MARGIN_I_ + 1) + r;
        int w = wb - (MARGIN_I_ + 1) + c;
        bool act = (i < WIN_ITEMS_) &&
                   ((unsigned)h < (unsigned)H_) && ((unsigned)w < (unsigned)W_);
        int hw = act ? (h * W_ + w) : 0;
        av[k] = act; hv[k] = h; wv[k] = w;
        fxv[k] = fxp[hw];
        fyv[k] = fyp[hw];
        v0v[k] = imgb[hw];
        v1v[k] = imgb[HW_ + hw];
        v2v[k] = imgb[2 * HW_ + hw];
    }

    // ---- phase 2: predicate + hit-test + LDS accumulate ----
    #pragma unroll
    for (int k = 0; k < 4; ++k) {
        if (!av[k]) continue;
        float fx = fxv[k], fy = fyv[k];
        // Must be the EXACT complement of outlier_kernel's predicate.
        if (!(fabsf(fx) <= MARGIN_ && fabsf(fy) <= MARGIN_)) continue;

        float x = ((float)wv[k] + fx) * (float)SCALE_;
        float y = ((float)hv[k] + fy) * (float)SCALE_;
        float x0f = floorf(x), y0f = floorf(y);
        int ix0 = (int)x0f - px0;   // tile-local
        int iy0 = (int)y0f - py0;
        bool cx0 = (unsigned)ix0 < (unsigned)TW_;
        bool cx1 = (unsigned)(ix0 + 1) < (unsigned)TW_;
        bool cy0 = (unsigned)iy0 < (unsigned)TH_;
        bool cy1 = (unsigned)(iy0 + 1) < (unsigned)TH_;
        if (!((cx0 | cx1) & (cy0 | cy1))) continue;

        float ax = x - x0f, ay = y - y0f;
        float wxs[2] = {1.0f - ax, ax};
        float wys[2] = {1.0f - ay, ay};
        bool cxs[2] = {cx0, cx1};
        bool cys[2] = {cy0, cy1};
        #pragma unroll
        for (int ky = 0; ky < 2; ++ky) {
            if (!cys[ky]) continue;
            #pragma unroll
            for (int kx = 0; kx < 2; ++kx) {
                if (!cxs[kx]) continue;
                float wt = wxs[kx] * wys[ky];
                int la = (iy0 + ky) * TW_ + (ix0 + kx);
                atomicAdd(&acc[la], v0v[k] * wt);
                atomicAdd(&acc[la + PLANE_STRIDE_], v1v[k] * wt);
                atomicAdd(&acc[la + 2 * PLANE_STRIDE_], v2v[k] * wt);
            }
        }
    }
    __syncthreads();

    // ---- phase 3: exclusive coalesced nontemporal float4 write-out ----
    const size_t outb = (size_t)b * C_ * Ho_ * Wo_;
    const int F4_PER_PLANE = TH_ * TW_ / 4;        // 640
    const int F4_PER_ROW   = TW_ / 4;              // 16
    for (int j = threadIdx.x; j < C_ * F4_PER_PLANE; j += 256) {
        int ch  = j / F4_PER_PLANE;
        int rem = j - ch * F4_PER_PLANE;
        int yy  = rem / F4_PER_ROW;
        int xx4 = rem - yy * F4_PER_ROW;
        f32x4 v = *reinterpret_cast<const f32x4*>(&acc[ch * PLANE_STRIDE_ + yy * TW_ + xx4 * 4]);
        __builtin_nontemporal_store(v,
            reinterpret_cast<f32x4*>(
                &out[outb + (size_t)ch * Ho_ * Wo_ + (size_t)(py0 + yy) * Wo_ + px0 + xx4 * 4]));
    }
}

// Pixels with |flow| > MARGIN_: exact global-atomic splat (runs AFTER tile writes).
__global__ __launch_bounds__(256) void outlier_kernel(const float* __restrict__ img,
                                                      const float* __restrict__ flow,
                                                      float* __restrict__ out) {
    int idx = blockIdx.x * 256 + threadIdx.x;   // grid exactly NPIX_/256
    int w = idx % W_;
    int t = idx / W_;
    int h = t % H_;
    int b = t / H_;
    int hw = h * W_ + w;
    float fx = flow[(b * 2 + 0) * HW_ + hw];
    float fy = flow[(b * 2 + 1) * HW_ + hw];
    if (fabsf(fx) <= MARGIN_ && fabsf(fy) <= MARGIN_) return;   // handled by tile pass

    float x = ((float)w + fx) * (float)SCALE_;
    float y = ((float)h + fy) * (float)SCALE_;
    float x0f = floorf(x), y0f = floorf(y);
    float ax = x - x0f, ay = y - y0f;
    int ix0 = (int)x0f, iy0 = (int)y0f;
    const float* imgb = img + (size_t)b * C_ * HW_;
    float v0 = imgb[hw];
    float v1 = imgb[HW_ + hw];
    float v2 = imgb[2 * HW_ + hw];
    const size_t out_b = (size_t)b * C_ * Ho_ * Wo_;
    const size_t chs = (size_t)Ho_ * Wo_;
    float wxs[2] = {1.0f - ax, ax};
    float wys[2] = {1.0f - ay, ay};
    #pragma unroll
    for (int ky = 0; ky < 2; ++ky) {
        int yi = iy0 + ky;
        if ((unsigned)yi >= (unsigned)Ho_) continue;
        #pragma unroll
        for (int kx = 0; kx < 2; ++kx) {
            int xi = ix0 + kx;
            if ((unsigned)xi >= (unsigned)Wo_) continue;
            float wt = wxs[kx] * wys[ky];
            size_t base = out_b + (size_t)yi * Wo_ + (size_t)xi;
            atomicAdd(&out[base + 0 * chs], v0 * wt);
            atomicAdd(&out[base + 1 * chs], v1 * wt);
            atomicAdd(&out[base + 2 * chs], v2 * wt);
        }
    }
}

// ---------------- fallback: naive global-atomic splat (scale != 4) ----------------
__global__ __launch_bounds__(256) void splat_naive(const float* __restrict__ img,
                                                   const float* __restrict__ flow,
                                                   const int* __restrict__ scale_p,
                                                   float* __restrict__ out) {
    int idx = blockIdx.x * blockDim.x + threadIdx.x;
    if (idx >= NPIX_) return;
    const int s = *scale_p;
    const int Ho = H_ * s, Wo = W_ * s;
    int w = idx % W_;
    int t = idx / W_;
    int h = t % H_;
    int b = t / H_;
    const int hw = h * W_ + w;
    float fx = flow[((b * 2 + 0) * H_) * W_ + hw];
    float fy = flow[((b * 2 + 1) * H_) * W_ + hw];
    float x = ((float)w + fx) * (float)s;
    float y = ((float)h + fy) * (float)s;
    float x0f = floorf(x), y0f = floorf(y);
    float ax = x - x0f, ay = y - y0f;
    int ix0 = (int)x0f, iy0 = (int)y0f;
    const size_t img_b = (size_t)b * C_ * HW_;
    float v0 = img[img_b + 0 * (size_t)HW_ + hw];
    float v1 = img[img_b + 1 * (size_t)HW_ + hw];
    float v2 = img[img_b + 2 * (size_t)HW_ + hw];
    const size_t out_b = (size_t)b * C_ * Ho * Wo;
    const size_t out_chs = (size_t)Ho * Wo;
    float wxs[2] = {1.0f - ax, ax};
    float wys[2] = {1.0f - ay, ay};
    #pragma unroll
    for (int ky = 0; ky < 2; ++ky) {
        int yi = iy0 + ky;
        if (yi < 0 || yi > Ho - 1) continue;
        #pragma unroll
        for (int kx = 0; kx < 2; ++kx) {
            int xi = ix0 + kx;
            if (xi < 0 || xi > Wo - 1) continue;
            float wt = wxs[kx] * wys[ky];
            size_t base = out_b + (size_t)yi * Wo + (size_t)xi;
            atomicAdd(&out[base + 0 * out_chs], v0 * wt);
            atomicAdd(&out[base + 1 * out_chs], v1 * wt);
            atomicAdd(&out[base + 2 * out_chs], v2 * wt);
        }
    }
}

extern "C" void kernel_launch(void* const* d_in, const int* in_sizes, int n_in,
                              void* d_out, int out_size, void* d_ws, size_t ws_size,
                              hipStream_t stream) {
    const float* img   = (const float*)d_in[0];
    const float* flow  = (const float*)d_in[1];
    const int*   scale = (const int*)d_in[2];
    float* out = (float*)d_out;

    const bool scale4 = (out_size == B_ * C_ * Ho_ * Wo_);

    if (scale4) {
        warp_tile_kernel<<<NTILES_, 256, 0, stream>>>(img, flow, out);
        outlier_kernel<<<NPIX_ / 256, 256, 0, stream>>>(img, flow, out);
    } else {
        (void)hipMemsetAsync(out, 0, (size_t)out_size * sizeof(float), stream);
        splat_naive<<<(NPIX_ + 255) / 256, 256, 0, stream>>>(img, flow, scale, out);
    }
}